// Round 5
// baseline (514.016 us; speedup 1.0000x reference)
//
#include <hip/hip_runtime.h>

#define FEAT 128
#define RANGE 12800
#define NSLICE 64

typedef _Float16 half8 __attribute__((ext_vector_type(8)));
typedef float f32x4 __attribute__((ext_vector_type(4)));

// ---------- hist: src & dst partial histograms in one dispatch, ushort-packed ----------
__global__ __launch_bounds__(1024) void hist_kernel(const int* __restrict__ src,
                                                    const int* __restrict__ dst,
                                                    unsigned* __restrict__ partialD,
                                                    unsigned* __restrict__ partialS,
                                                    int E, int NP) {
    __shared__ unsigned hpk[RANGE / 2];
    int per = (NP / RANGE) * NSLICE;
    int b = blockIdx.x;
    int halfsel = b / per;           // 0 = dst histogram, 1 = src histogram
    int q = b % per;
    int r = q / NSLICE;
    int s = q % NSLICE;
    const int* arr = halfsel ? src : dst;
    unsigned* out = halfsel ? partialS : partialD;
    int v0 = r * RANGE;
    int tid = threadIdx.x;
    for (int i = tid; i < RANGE / 2; i += 1024) hpk[i] = 0;
    __syncthreads();
    int e0 = (int)((long long)E * s / NSLICE);
    int e1 = (int)((long long)E * (s + 1) / NSLICE);
    for (int e = e0 + tid; e < e1; e += 1024) {
        unsigned d = (unsigned)(arr[e] - v0);
        if (d < RANGE) atomicAdd(&hpk[d >> 1], (d & 1) ? 65536u : 1u);
    }
    __syncthreads();
    size_t wbase = ((size_t)s * NP + v0) >> 1;
    for (int i = tid; i < RANGE / 2; i += 1024) out[wbase + i] = hpk[i];
}

// ---------- scan phase 1: per-node slice-sums + deg_in + norms ----------
__global__ __launch_bounds__(256) void scanp1_kernel(const unsigned short* __restrict__ pD,
                                                     const unsigned short* __restrict__ pS,
                                                     int* __restrict__ blockSums,
                                                     float* __restrict__ ns,
                                                     float* __restrict__ nd,
                                                     int NP, int n) {
    __shared__ int buf[256];
    int tid = threadIdx.x;
    int v = blockIdx.x * 256 + tid;
    int ssum = 0, osum = 0;
    #pragma unroll
    for (int s = 0; s < NSLICE; ++s) {
        ssum += pD[(size_t)s * NP + v];
        osum += pS[(size_t)s * NP + v];
    }
    if (v < n) {
        ns[v] = 1.0f / sqrtf((float)(osum < 1 ? 1 : osum));
        nd[v] = 1.0f / sqrtf((float)(ssum < 1 ? 1 : ssum));
    }
    buf[tid] = ssum;
    __syncthreads();
    #pragma unroll
    for (int off = 1; off < 256; off <<= 1) {
        int t = (tid >= off) ? buf[tid - off] : 0;
        __syncthreads();
        buf[tid] += t;
        __syncthreads();
    }
    if (tid == 255) blockSums[blockIdx.x] = buf[255];
}

// ---------- scan phase 2 ----------
__global__ __launch_bounds__(256) void scanp2_kernel(const int* __restrict__ blockSums,
                                                     int* __restrict__ blockOffs, int nb) {
    __shared__ int buf[256];
    int tid = threadIdx.x;
    int v = (tid < nb) ? blockSums[tid] : 0;
    buf[tid] = v;
    __syncthreads();
    #pragma unroll
    for (int off = 1; off < 256; off <<= 1) {
        int t = (tid >= off) ? buf[tid - off] : 0;
        __syncthreads();
        buf[tid] += t;
        __syncthreads();
    }
    if (tid < nb) blockOffs[tid] = buf[tid] - v;
}

// ---------- scan phase 3: per-(node,slice) cursors + compact offsets ----------
__global__ __launch_bounds__(256) void scanp3_kernel(const unsigned short* __restrict__ pD,
                                                     const int* __restrict__ blockOffs,
                                                     int* __restrict__ cursorV,
                                                     int* __restrict__ offsc,
                                                     int NP, int n) {
    __shared__ int buf[256];
    int tid = threadIdx.x;
    int v = blockIdx.x * 256 + tid;
    int ssum = 0;
    #pragma unroll
    for (int s = 0; s < NSLICE; ++s) ssum += pD[(size_t)s * NP + v];
    buf[tid] = ssum;
    __syncthreads();
    #pragma unroll
    for (int off = 1; off < 256; off <<= 1) {
        int t = (tid >= off) ? buf[tid - off] : 0;
        __syncthreads();
        buf[tid] += t;
        __syncthreads();
    }
    int o = blockOffs[blockIdx.x] + buf[tid] - ssum;
    if (v <= n) offsc[v] = o;          // pad nodes have zero edges -> v==n gets total
    int* cv = cursorV + (size_t)v * NSLICE;
    #pragma unroll
    for (int s = 0; s < NSLICE; ++s) {
        int val = pD[(size_t)s * NP + v];
        cv[s] = o;
        o += val;
    }
}

// ---------- fill: place edges via LDS cursors (XCD-swizzled slices) ----------
__global__ __launch_bounds__(1024) void fill_kernel(const int* __restrict__ src,
                                                    const int* __restrict__ dst,
                                                    const int* __restrict__ cursorV,
                                                    int* __restrict__ esrc, int E, int NP) {
    __shared__ int cur[RANGE];
    int b = blockIdx.x;
    int r = b / NSLICE;
    int inner = b % NSLICE;
    int s = ((inner & 7) << 3) | (inner >> 3);
    int v0 = r * RANGE;
    int tid = threadIdx.x;
    for (int i = tid; i < RANGE; i += 1024)
        cur[i] = cursorV[(size_t)(v0 + i) * NSLICE + s];
    __syncthreads();
    int e0 = (int)((long long)E * s / NSLICE);
    int e1 = (int)((long long)E * (s + 1) / NSLICE);
    for (int e = e0 + tid; e < e1; e += 1024) {
        unsigned dd = (unsigned)(dst[e] - v0);
        if (dd < RANGE) {
            int p = atomicAdd(&cur[dd], 1);
            esrc[p] = src[e];
        }
    }
}

// ---------- prescale: xh = fp16(in_feat * ns) ----------
__global__ void prescale_kernel(const float* __restrict__ x, const float* __restrict__ ns,
                                _Float16* __restrict__ xh, int n) {
    int i = blockIdx.x * blockDim.x + threadIdx.x;   // one thread per 8 elements
    if (i >= n * (FEAT / 8)) return;
    int v = i >> 4;
    float w = ns[v];
    float4 t0 = ((const float4*)x)[i * 2];
    float4 t1 = ((const float4*)x)[i * 2 + 1];
    half8 h;
    h[0] = (_Float16)(t0.x * w); h[1] = (_Float16)(t0.y * w);
    h[2] = (_Float16)(t0.z * w); h[3] = (_Float16)(t0.w * w);
    h[4] = (_Float16)(t1.x * w); h[5] = (_Float16)(t1.y * w);
    h[6] = (_Float16)(t1.z * w); h[7] = (_Float16)(t1.w * w);
    ((float4*)xh)[i] = __builtin_bit_cast(float4, h);
}

// ---------- W prep: fp16 value+residual, transposed to [col][k] ----------
__global__ __launch_bounds__(256) void wprep_kernel(const float* __restrict__ Wa,
                                                    const float* __restrict__ Wb,
                                                    const float* __restrict__ Wc,
                                                    const float* __restrict__ Wd,
                                                    const float* __restrict__ We,
                                                    _Float16* __restrict__ w16t,
                                                    _Float16* __restrict__ wrt) {
    int gid = blockIdx.x * 256 + threadIdx.x;        // 5 * 128 * 128 = 81920
    int l = gid >> 14;
    int idx = gid & 16383;
    int col = idx >> 7;
    int k = idx & 127;
    const float* Wp = (l == 0) ? Wa : (l == 1) ? Wb : (l == 2) ? Wc : (l == 3) ? Wd : We;
    float w = Wp[k * FEAT + col];
    _Float16 h = (_Float16)w;
    _Float16 r = (_Float16)(w - (float)h);
    w16t[gid] = h;
    wrt[gid] = r;
}

// ---------- fused agg + GEMM: 64 dst-nodes per block, 512 threads (8 waves) ----------
// Phase 1: half-wave-per-node fp16 gather -> fp32 LDS tile m[64][132] (nd applied).
// Phase 2: MFMA f16 value+residual; A split from LDS fp32 in regs; W16/Wr fragments
//          read directly from L2-resident transposed arrays (no W staging).
// acc = A16*W16 + A16*Wr + Ar*W16   (drops Ar*Wr ~ 2.4e-7 rel)
template<int MODE>   // 0: relu*ns -> fp16 out   1: last layer (fp32 h + threshold)
__global__ __launch_bounds__(512, 4) void fused_kernel(const _Float16* __restrict__ x,
                                                       const int* __restrict__ offs,
                                                       const int* __restrict__ esrc,
                                                       const float* __restrict__ nd,
                                                       const float* __restrict__ nsv,
                                                       const _Float16* __restrict__ w16t,
                                                       const _Float16* __restrict__ wrt,
                                                       const float* __restrict__ bias,
                                                       _Float16* __restrict__ outh,
                                                       float* __restrict__ outf,
                                                       float* __restrict__ out2, int n) {
    __shared__ float ms[64][132];      // +4 pad: fragment reads are 2-way (free) on 32 banks
    int tid = threadIdx.x;
    int r0 = blockIdx.x * 64;

    // ---- phase 1: gather ----
    int hw = tid >> 5;                 // 16 half-waves
    int lane = tid & 31;
    int q = lane >> 4;                 // edge stream 0/1
    int c = lane & 15;                 // 16 lanes x 16B cover a 128-half row
    #pragma unroll
    for (int t = 0; t < 4; ++t) {
        int row = hw * 4 + t;
        int v = r0 + row;
        if (v < n) {
            int s0 = offs[v], s1 = offs[v + 1];
            float a0[8] = {0,0,0,0,0,0,0,0};
            float a1[8] = {0,0,0,0,0,0,0,0};
            float a2[8] = {0,0,0,0,0,0,0,0};
            float a3[8] = {0,0,0,0,0,0,0,0};
            int j = s0 + q;
            for (; j + 6 < s1; j += 8) {
                int e0 = esrc[j], e1 = esrc[j + 2], e2 = esrc[j + 4], e3 = esrc[j + 6];
                float4 r0v = ((const float4*)(x + (size_t)e0 * FEAT))[c];
                float4 r1v = ((const float4*)(x + (size_t)e1 * FEAT))[c];
                float4 r2v = ((const float4*)(x + (size_t)e2 * FEAT))[c];
                float4 r3v = ((const float4*)(x + (size_t)e3 * FEAT))[c];
                half8 h0 = __builtin_bit_cast(half8, r0v);
                half8 h1 = __builtin_bit_cast(half8, r1v);
                half8 h2 = __builtin_bit_cast(half8, r2v);
                half8 h3 = __builtin_bit_cast(half8, r3v);
                #pragma unroll
                for (int k = 0; k < 8; ++k) {
                    a0[k] += (float)h0[k];
                    a1[k] += (float)h1[k];
                    a2[k] += (float)h2[k];
                    a3[k] += (float)h3[k];
                }
            }
            for (; j < s1; j += 2) {
                int e0 = esrc[j];
                float4 r0v = ((const float4*)(x + (size_t)e0 * FEAT))[c];
                half8 h0 = __builtin_bit_cast(half8, r0v);
                #pragma unroll
                for (int k = 0; k < 8; ++k) a0[k] += (float)h0[k];
            }
            float r[8];
            #pragma unroll
            for (int k = 0; k < 8; ++k) r[k] = (a0[k] + a1[k]) + (a2[k] + a3[k]);
            #pragma unroll
            for (int k = 0; k < 8; ++k) r[k] += __shfl_xor(r[k], 16);  // cross-stream
            if (q == 0) {
                float sc = nd[v];
                float4 o0, o1;
                o0.x = r[0] * sc; o0.y = r[1] * sc; o0.z = r[2] * sc; o0.w = r[3] * sc;
                o1.x = r[4] * sc; o1.y = r[5] * sc; o1.z = r[6] * sc; o1.w = r[7] * sc;
                *(float4*)&ms[row][c * 8] = o0;
                *(float4*)&ms[row][c * 8 + 4] = o1;
            }
        } else if (q == 0) {
            float4 z = make_float4(0.f, 0.f, 0.f, 0.f);
            *(float4*)&ms[row][c * 8] = z;
            *(float4*)&ms[row][c * 8 + 4] = z;
        }
    }
    __syncthreads();

    // ---- phase 2: MFMA ----
    int lane64 = tid & 63;
    int w = tid >> 6;                  // 8 waves: 4 row-groups x 2 col-groups
    int l15 = lane64 & 15;
    int qq = lane64 >> 4;
    int rw = w & 3, cw = w >> 2;
    int rbase = rw * 16 + l15;
    int cbase = cw * 64;

    f32x4 acc[4] = {{0.f,0.f,0.f,0.f},{0.f,0.f,0.f,0.f},{0.f,0.f,0.f,0.f},{0.f,0.f,0.f,0.f}};
    #pragma unroll
    for (int ks = 0; ks < 4; ++ks) {
        int chunk = ks * 4 + qq;       // k = chunk*8 .. +8
        float4 f0 = *(const float4*)&ms[rbase][chunk * 8];
        float4 f1 = *(const float4*)&ms[rbase][chunk * 8 + 4];
        half8 a16, ar;
        a16[0] = (_Float16)f0.x; a16[1] = (_Float16)f0.y;
        a16[2] = (_Float16)f0.z; a16[3] = (_Float16)f0.w;
        a16[4] = (_Float16)f1.x; a16[5] = (_Float16)f1.y;
        a16[6] = (_Float16)f1.z; a16[7] = (_Float16)f1.w;
        ar[0] = (_Float16)(f0.x - (float)a16[0]); ar[1] = (_Float16)(f0.y - (float)a16[1]);
        ar[2] = (_Float16)(f0.z - (float)a16[2]); ar[3] = (_Float16)(f0.w - (float)a16[3]);
        ar[4] = (_Float16)(f1.x - (float)a16[4]); ar[5] = (_Float16)(f1.y - (float)a16[5]);
        ar[6] = (_Float16)(f1.z - (float)a16[6]); ar[7] = (_Float16)(f1.w - (float)a16[7]);
        #pragma unroll
        for (int ct = 0; ct < 4; ++ct) {
            int col = cbase + ct * 16 + l15;
            half8 b16 = *(const half8*)(w16t + (size_t)col * FEAT + chunk * 8);
            half8 br  = *(const half8*)(wrt  + (size_t)col * FEAT + chunk * 8);
            acc[ct] = __builtin_amdgcn_mfma_f32_16x16x32_f16(a16, b16, acc[ct], 0, 0, 0);
            acc[ct] = __builtin_amdgcn_mfma_f32_16x16x32_f16(a16, br,  acc[ct], 0, 0, 0);
            acc[ct] = __builtin_amdgcn_mfma_f32_16x16x32_f16(ar,  b16, acc[ct], 0, 0, 0);
        }
    }

    // epilogue: C/D layout col=lane&15, row=(lane>>4)*4+reg
    int rloc = rw * 16 + qq * 4;
    float scv[4];
    #pragma unroll
    for (int reg = 0; reg < 4; ++reg) {
        int row = r0 + rloc + reg;
        scv[reg] = (MODE == 0 && row < n) ? nsv[row] : 1.0f;
    }
    #pragma unroll
    for (int ct = 0; ct < 4; ++ct) {
        int col = cbase + ct * 16 + l15;
        float b = bias[col];
        #pragma unroll
        for (int reg = 0; reg < 4; ++reg) {
            int row = r0 + rloc + reg;
            if (row < n) {
                float h = acc[ct][reg] + b;
                h = h > 0.f ? h : 0.f;
                if (MODE == 0) {
                    outh[(size_t)row * FEAT + col] = (_Float16)(h * scv[reg]);
                } else {
                    outf[(size_t)row * FEAT + col] = h;
                    out2[(size_t)row * FEAT + col] = h >= 0.5f ? 1.f : 0.f;
                }
            }
        }
    }
}

extern "C" void kernel_launch(void* const* d_in, const int* in_sizes, int n_in,
                              void* d_out, int out_size, void* d_ws, size_t ws_size,
                              hipStream_t stream) {
    const float* in_feat = (const float*)d_in[0];
    const int*   src     = (const int*)d_in[1];
    const int*   dst     = (const int*)d_in[2];
    const float* W[5] = {(const float*)d_in[3], (const float*)d_in[5], (const float*)d_in[7],
                         (const float*)d_in[9], (const float*)d_in[11]};
    const float* B[5] = {(const float*)d_in[4], (const float*)d_in[6], (const float*)d_in[8],
                         (const float*)d_in[10], (const float*)d_in[12]};
    const int E = in_sizes[1];
    const int N = in_sizes[0] / FEAT;
    const int NRANGE = (N + RANGE - 1) / RANGE;       // 4
    const int NP = NRANGE * RANGE;                    // 51200
    const size_t MTOT = (size_t)NP * NSLICE;          // 3,276,800

    char* ws = (char*)d_ws;
    size_t off = 0;
    auto alloc = [&](size_t bytes) { size_t o = off; off += (bytes + 255) & ~size_t(255); return o; };
    unsigned* partialD = (unsigned*)(ws + alloc(MTOT * 2));
    size_t    pS_off   = alloc(MTOT * 2);
    unsigned* partialS = (unsigned*)(ws + pS_off);
    int*      esrc     = (int*)(ws + pS_off);          // aliases partialS (dead after scanp1)
    size_t    cV_off   = alloc(MTOT * 4);
    int*      cursorV  = (int*)(ws + cV_off);
    _Float16* xhA      = (_Float16*)(ws + cV_off);     // aliases cursorV (dead after fill); 12.8MB <= 13.1MB
    float*    ns       = (float*)(ws + alloc((size_t)N * 4));
    float*    nd       = (float*)(ws + alloc((size_t)N * 4));
    int*      offsc    = (int*)(ws + alloc((size_t)(N + 1) * 4));
    int*      blockSums = (int*)(ws + alloc(1024));
    int*      blockOffs = (int*)(ws + alloc(1024));
    _Float16* w16t     = (_Float16*)(ws + alloc(5 * 16384 * 2));
    _Float16* wrt      = (_Float16*)(ws + alloc(5 * 16384 * 2));
    _Float16* xhB      = (_Float16*)(ws + alloc((size_t)N * FEAT * 2));

    float* out_h = (float*)d_out;                     // final h
    float* out_c = out_h + (size_t)N * FEAT;          // threshold output

    const int histBlocks = 2 * NRANGE * NSLICE;       // 512
    const int scanBlocks = NP / 256;                  // 200
    hist_kernel<<<histBlocks, 1024, 0, stream>>>(src, dst, partialD, partialS, E, NP);
    scanp1_kernel<<<scanBlocks, 256, 0, stream>>>((const unsigned short*)partialD,
                                                  (const unsigned short*)partialS,
                                                  blockSums, ns, nd, NP, N);
    scanp2_kernel<<<1, 256, 0, stream>>>(blockSums, blockOffs, scanBlocks);
    scanp3_kernel<<<scanBlocks, 256, 0, stream>>>((const unsigned short*)partialD,
                                                  blockOffs, cursorV, offsc, NP, N);
    fill_kernel<<<NRANGE * NSLICE, 1024, 0, stream>>>(src, dst, cursorV, esrc, E, NP);
    wprep_kernel<<<320, 256, 0, stream>>>(W[0], W[1], W[2], W[3], W[4], w16t, wrt);
    // prescale AFTER fill: xhA aliases cursorV
    prescale_kernel<<<(N * (FEAT / 8) + 255) / 256, 256, 0, stream>>>(in_feat, ns, xhA, N);

    const int fusedBlocks = (N + 63) / 64;            // 782

    for (int l = 0; l < 5; ++l) {
        const _Float16* xin = (l & 1) ? xhB : xhA;
        _Float16*       xout = (l & 1) ? xhA : xhB;
        if (l < 4)
            fused_kernel<0><<<fusedBlocks, 512, 0, stream>>>(xin, offsc, esrc, nd, ns,
                                                             w16t + (size_t)l * 16384,
                                                             wrt + (size_t)l * 16384, B[l],
                                                             xout, nullptr, nullptr, N);
        else
            fused_kernel<1><<<fusedBlocks, 512, 0, stream>>>(xin, offsc, esrc, nd, nullptr,
                                                             w16t + (size_t)l * 16384,
                                                             wrt + (size_t)l * 16384, B[l],
                                                             nullptr, out_h, out_c, N);
    }
}